// Round 1
// baseline (972.514 us; speedup 1.0000x reference)
//
#include <hip/hip_runtime.h>

// ScaledDotProductAttention over groups axis.
// B=2, G=32, H=128 (=8 heads x d=16), S=4096. fp32 in/out.
// Block = (b, 16-s-tile), 1024 threads = 16 waves; wave w owns s-position w and
// loops h=0..7 so head-means accumulate in registers (no atomics).
// QK^T: one v_mfma_f32_32x32x16_bf16 per (s,h): A=K (m=f), B=Q (n=g) -> D[f][g],
// so softmax over f is 16 regs + one shfl_xor(32).
// PV: VALU with broadcast LDS reads of V. x staged via LDS (fp32, quad-swizzled)
// for coalesced float4 global stores. Means staged in LDS at the end.
//
// R1: kill scratch spills. Dynamic LDS (128KB -> 1 block/CU = 4 waves/EU) is
// invisible to the register allocator, which targeted 8 waves/EU (<=64 VGPR)
// and spilled ~30 regs/thread to scratch (~1.6 GB of hidden HBM traffic; the
// measured 6x write amplification). __launch_bounds__(1024,4) raises the VGPR
// budget to 128 at zero occupancy cost; p[16] folded into C[] to cut peak
// pressure a further 16 regs.

typedef __attribute__((ext_vector_type(8))) short short8;
typedef __attribute__((ext_vector_type(16))) float floatx16;

#define SQ_LEN 4096
#define TS 16              // s-positions per block
#define SLICE_U 520        // ushorts per s-slice (512 + 8 pad for staging-store bank spread)
#define SLICE_DW 260
#define TILE_U (TS * SLICE_U)          // 8320 ushorts per tile
#define SMEM_BYTES 131072              // max(QKV 49920 + Xs 32768, means 131072)

__device__ __forceinline__ unsigned short f2bf(float x) {
  unsigned u = __float_as_uint(x);
  u = u + 0x7FFFu + ((u >> 16) & 1u);          // RNE
  return (unsigned short)(u >> 16);
}
__device__ __forceinline__ float bf2f(short s) {
  return __uint_as_float(((unsigned)(unsigned short)s) << 16);
}
__device__ __forceinline__ unsigned pack2(float lo, float hi) {
  return (unsigned)f2bf(lo) | ((unsigned)f2bf(hi) << 16);
}

// Stage one 512-row x 16-s tile (rows = g*16+d, channel = h*16+d) into bf16 LDS
// layout [s][row(16 ushorts)] with slice stride SLICE_U. Fully coalesced global
// float4 loads (16 rows x 64B per wave-instr); packed ushort2 LDS stores.
__device__ __forceinline__ void stage_tile(const float* __restrict__ src,
                                           unsigned* dst32, int b, int h, int s0,
                                           int tid, float scale) {
  int pr = tid >> 2, q4 = tid & 3;   // row-pair 0..255, s-quad 0..3
  int r0 = pr << 1;
  int gg = r0 >> 4, d0 = r0 & 15;    // rows r0,r0+1 share gg
  const float* p0 = src + (((long)b * 32 + gg) * 128 + h * 16 + d0) * SQ_LEN + s0 + (q4 << 2);
  float4 a0 = *(const float4*)p0;
  float4 a1 = *(const float4*)(p0 + SQ_LEN);
  int sb = q4 << 2;
  dst32[(sb + 0) * SLICE_DW + pr] = pack2(a0.x * scale, a1.x * scale);
  dst32[(sb + 1) * SLICE_DW + pr] = pack2(a0.y * scale, a1.y * scale);
  dst32[(sb + 2) * SLICE_DW + pr] = pack2(a0.z * scale, a1.z * scale);
  dst32[(sb + 3) * SLICE_DW + pr] = pack2(a0.w * scale, a1.w * scale);
}

__global__ __launch_bounds__(1024, 4) void attn_kernel(
    const float* __restrict__ q, const float* __restrict__ k,
    const float* __restrict__ v, float* __restrict__ xout,
    float* __restrict__ aout, float* __restrict__ lout) {
  extern __shared__ unsigned char smem[];
  unsigned short* Qs = (unsigned short*)smem;
  unsigned short* Ks = Qs + TILE_U;
  unsigned short* Vs = Ks + TILE_U;
  float* Xs = (float*)(smem + 3 * TILE_U * 2);   // 512 rows x 16 s fp32 (32 KB)

  const int tid = threadIdx.x;
  const int b = blockIdx.y;
  const int s0 = blockIdx.x * TS;
  const int wave = tid >> 6, lane = tid & 63;
  const int half = lane >> 5, lid = lane & 31;
  const int s_w = wave;                           // this wave's s within the tile
  // quad-XOR swizzle of the s index (keyed on g=lid) to spread LDS banks
  const int sswz = (s_w & 3) | ((((s_w >> 2) ^ (lid & 3)) & 3) << 2);

  float attn_sum[16], logit_sum[16];
#pragma unroll
  for (int r = 0; r < 16; ++r) { attn_sum[r] = 0.f; logit_sum[r] = 0.f; }

  stage_tile(q, (unsigned*)Qs, b, 0, s0, tid, 0.25f);  // scale=d^-0.5 folded in (exact)
  stage_tile(k, (unsigned*)Ks, b, 0, s0, tid, 1.0f);
  stage_tile(v, (unsigned*)Vs, b, 0, s0, tid, 1.0f);
  __syncthreads();

  for (int h = 0; h < 8; ++h) {
    // ---- QK^T via MFMA: A = K (m=f=lid), B = Q (n=g=lid), k-oct by half ----
    const unsigned short* qp = Qs + s_w * SLICE_U + lid * 16 + half * 8;
    const unsigned short* kp = Ks + s_w * SLICE_U + lid * 16 + half * 8;
    short8 qf = *(const short8*)qp;
    short8 kf = *(const short8*)kp;
    floatx16 C = {0.f, 0.f, 0.f, 0.f, 0.f, 0.f, 0.f, 0.f,
                  0.f, 0.f, 0.f, 0.f, 0.f, 0.f, 0.f, 0.f};
    C = __builtin_amdgcn_mfma_f32_32x32x16_bf16(kf, qf, C, 0, 0, 0);
    // C[r] = logits[f_r][g=lid], f_r = (r&3) + 8*(r>>2) + 4*half

    float m = -3.0e38f;
#pragma unroll
    for (int r = 0; r < 16; ++r) { logit_sum[r] += C[r]; m = fmaxf(m, C[r]); }
    m = fmaxf(m, __shfl_xor(m, 32));
    // overwrite C with exp(C - m): p[] folded into C to cut register pressure
    float l = 0.f;
#pragma unroll
    for (int r = 0; r < 16; ++r) { float e = __expf(C[r] - m); C[r] = e; l += e; }
    l += __shfl_xor(l, 32);
    const float inv = 1.0f / l;

    // ---- PV: x[g][d] += attn[f] * v[f][d], V broadcast from LDS ----
    float xacc[16];
#pragma unroll
    for (int d = 0; d < 16; ++d) xacc[d] = 0.f;
#pragma unroll
    for (int r = 0; r < 16; ++r) {
      float a = C[r] * inv;
      attn_sum[r] += a;
      int f = (r & 3) + ((r >> 2) << 3) + (half << 2);
      const unsigned short* vp = Vs + s_w * SLICE_U + f * 16;
      short8 vlo = *(const short8*)vp;
      short8 vhi = *(const short8*)(vp + 8);
#pragma unroll
      for (int j = 0; j < 8; ++j) {
        xacc[j]     = fmaf(a, bf2f(vlo[j]), xacc[j]);
        xacc[j + 8] = fmaf(a, bf2f(vhi[j]), xacc[j + 8]);
      }
    }
#pragma unroll
    for (int d = 0; d < 16; ++d) xacc[d] += __shfl_xor(xacc[d], 32);
    // store x into swizzled LDS stage; each half stores its 8 d's
#pragma unroll
    for (int j = 0; j < 8; ++j) {
      int d = (half << 3) + j;
      Xs[(lid * 16 + d) * 16 + sswz] = xacc[d];
    }
    __syncthreads();   // QKV free; Xs(h) ready

    if (h < 7) {       // stage next head (overlaps x writeout below)
      stage_tile(q, (unsigned*)Qs, b, h + 1, s0, tid, 0.25f);
      stage_tile(k, (unsigned*)Ks, b, h + 1, s0, tid, 1.0f);
      stage_tile(v, (unsigned*)Vs, b, h + 1, s0, tid, 1.0f);
    }
    // ---- coalesced x writeout for this h: 512 rows x 4 float4 ----
    {
      int it = tid;
#pragma unroll
      for (int c = 0; c < 2; ++c, it += 1024) {
        int row = it >> 2, sq = it & 3;
        int gg = row >> 4, dd = row & 15;
        float4 val = *(const float4*)&Xs[row * 16 + ((sq ^ (gg & 3)) << 2)];
        *(float4*)(xout + (((long)b * 32 + gg) * 128 + h * 16 + dd) * SQ_LEN +
                   s0 + (sq << 2)) = val;
      }
    }
    __syncthreads();   // Xs free for next h; staged QKV visible
  }

  // ---- head-mean writeout: stage sums in LDS (overlays QKV+Xs), float4 stores ----
  float* A = (float*)smem;        // attn_mean stage: 1024 rows x 16 s (64 KB)
  float* L = A + 16384;           // logits_mean stage (64 KB)
#pragma unroll
  for (int r = 0; r < 16; ++r) {
    int f = (r & 3) + ((r >> 2) << 3) + (half << 2);
    A[(lid * 32 + f) * 16 + sswz] = attn_sum[r] * 0.125f;
    L[(lid * 32 + f) * 16 + sswz] = logit_sum[r] * 0.125f;
  }
  __syncthreads();
  for (int it = tid; it < 8192; it += 1024) {
    int arr = it >> 12;
    int rem = it & 4095;
    int row = rem >> 2, sq = rem & 3;
    int gg = row >> 5, ff = row & 31;
    const float* SRC = arr ? L : A;
    float4 val = *(const float4*)&SRC[row * 16 + ((sq ^ (gg & 3)) << 2)];
    float* dst = (arr ? lout : aout) +
                 (((long)b * 32 + gg) * 32 + ff) * SQ_LEN + s0 + (sq << 2);
    *(float4*)dst = val;
  }
}

extern "C" void kernel_launch(void* const* d_in, const int* in_sizes, int n_in,
                              void* d_out, int out_size, void* d_ws, size_t ws_size,
                              hipStream_t stream) {
  const float* q = (const float*)d_in[0];
  const float* k = (const float*)d_in[1];
  const float* v = (const float*)d_in[2];
  float* xout = (float*)d_out;                   // (2,4096,4096)
  float* aout = xout + 33554432;                 // (2,32,32,4096)
  float* lout = xout + 41943040;                 // (2,32,32,4096)
  (void)hipFuncSetAttribute((const void*)attn_kernel,
                            hipFuncAttributeMaxDynamicSharedMemorySize, SMEM_BYTES);
  attn_kernel<<<dim3(SQ_LEN / TS, 2), 1024, SMEM_BYTES, stream>>>(q, k, v, xout, aout, lout);
}

// Round 2
// 914.055 us; speedup vs baseline: 1.0640x; 1.0640x over previous
//
#include <hip/hip_runtime.h>

// ScaledDotProductAttention over groups axis.
// B=2, G=32, H=128 (=8 heads x d=16), S=4096. fp32 in/out.
// Block = (b, 16-s-tile), 1024 threads = 16 waves; wave w owns s-position w and
// loops h=0..7 so head-means accumulate in registers (no atomics).
// QK^T: one v_mfma_f32_32x32x16_bf16 per (s,h): A=K (m=f), B=Q (n=g) -> D[f][g],
// so softmax over f is 16 regs + one shfl_xor(32).
// PV: VALU with broadcast LDS reads of V. x staged via LDS (fp32, quad-swizzled)
// for coalesced float4 global stores. Means staged in LDS at the end.
//
// R2: XCD-locality block swizzle. Every global segment is 64B (16 s x 4B) with
// ~16KB stride -- half a 128B line; the other half belongs to the adjacent
// s-tile. Default dispatch round-robins adjacent tiles onto DIFFERENT XCDs
// (non-coherent L2s), so every line is fetched twice half-used and x/means
// stores are 64B-partial (RMW + partial dirty evictions): measured FETCH 3x,
// WRITE 6x ideal. Remap so XCD k owns a contiguous run of s-tiles: line
// halves meet in the same L2 -> dense 128B fetches, full-line writebacks.

typedef __attribute__((ext_vector_type(8))) short short8;
typedef __attribute__((ext_vector_type(16))) float floatx16;

#define SQ_LEN 4096
#define TS 16              // s-positions per block
#define SLICE_U 520        // ushorts per s-slice (512 + 8 pad for staging-store bank spread)
#define SLICE_DW 260
#define TILE_U (TS * SLICE_U)          // 8320 ushorts per tile
#define SMEM_BYTES 131072              // max(QKV 49920 + Xs 32768, means 131072)

__device__ __forceinline__ unsigned short f2bf(float x) {
  unsigned u = __float_as_uint(x);
  u = u + 0x7FFFu + ((u >> 16) & 1u);          // RNE
  return (unsigned short)(u >> 16);
}
__device__ __forceinline__ float bf2f(short s) {
  return __uint_as_float(((unsigned)(unsigned short)s) << 16);
}
__device__ __forceinline__ unsigned pack2(float lo, float hi) {
  return (unsigned)f2bf(lo) | ((unsigned)f2bf(hi) << 16);
}

// Stage one 512-row x 16-s tile (rows = g*16+d, channel = h*16+d) into bf16 LDS
// layout [s][row(16 ushorts)] with slice stride SLICE_U. Fully coalesced global
// float4 loads (16 rows x 64B per wave-instr); packed ushort2 LDS stores.
__device__ __forceinline__ void stage_tile(const float* __restrict__ src,
                                           unsigned* dst32, int b, int h, int s0,
                                           int tid, float scale) {
  int pr = tid >> 2, q4 = tid & 3;   // row-pair 0..255, s-quad 0..3
  int r0 = pr << 1;
  int gg = r0 >> 4, d0 = r0 & 15;    // rows r0,r0+1 share gg
  const float* p0 = src + (((long)b * 32 + gg) * 128 + h * 16 + d0) * SQ_LEN + s0 + (q4 << 2);
  float4 a0 = *(const float4*)p0;
  float4 a1 = *(const float4*)(p0 + SQ_LEN);
  int sb = q4 << 2;
  dst32[(sb + 0) * SLICE_DW + pr] = pack2(a0.x * scale, a1.x * scale);
  dst32[(sb + 1) * SLICE_DW + pr] = pack2(a0.y * scale, a1.y * scale);
  dst32[(sb + 2) * SLICE_DW + pr] = pack2(a0.z * scale, a1.z * scale);
  dst32[(sb + 3) * SLICE_DW + pr] = pack2(a0.w * scale, a1.w * scale);
}

__global__ __launch_bounds__(1024, 4) void attn_kernel(
    const float* __restrict__ q, const float* __restrict__ k,
    const float* __restrict__ v, float* __restrict__ xout,
    float* __restrict__ aout, float* __restrict__ lout) {
  extern __shared__ unsigned char smem[];
  unsigned short* Qs = (unsigned short*)smem;
  unsigned short* Ks = Qs + TILE_U;
  unsigned short* Vs = Ks + TILE_U;
  float* Xs = (float*)(smem + 3 * TILE_U * 2);   // 512 rows x 16 s fp32 (32 KB)

  const int tid = threadIdx.x;
  // ---- XCD-locality swizzle: dispatch order flat = by*gridDim.x + bx,
  // XCD = flat % 8. Give each XCD a contiguous run of 64 (b, s-tile) slots so
  // adjacent s-tiles (the two 64B halves of every 128B line) share one L2.
  {
  }
  const int flat = blockIdx.y * gridDim.x + blockIdx.x;   // 0..511
  const int nf = (flat & 7) * 64 + (flat >> 3);           // bijective, 512%8==0
  const int b = nf >> 8;
  const int s0 = (nf & 255) * TS;
  const int wave = tid >> 6, lane = tid & 63;
  const int half = lane >> 5, lid = lane & 31;
  const int s_w = wave;                           // this wave's s within the tile
  // quad-XOR swizzle of the s index (keyed on g=lid) to spread LDS banks
  const int sswz = (s_w & 3) | ((((s_w >> 2) ^ (lid & 3)) & 3) << 2);

  float attn_sum[16], logit_sum[16];
#pragma unroll
  for (int r = 0; r < 16; ++r) { attn_sum[r] = 0.f; logit_sum[r] = 0.f; }

  stage_tile(q, (unsigned*)Qs, b, 0, s0, tid, 0.25f);  // scale=d^-0.5 folded in (exact)
  stage_tile(k, (unsigned*)Ks, b, 0, s0, tid, 1.0f);
  stage_tile(v, (unsigned*)Vs, b, 0, s0, tid, 1.0f);
  __syncthreads();

  for (int h = 0; h < 8; ++h) {
    // ---- QK^T via MFMA: A = K (m=f=lid), B = Q (n=g=lid), k-oct by half ----
    const unsigned short* qp = Qs + s_w * SLICE_U + lid * 16 + half * 8;
    const unsigned short* kp = Ks + s_w * SLICE_U + lid * 16 + half * 8;
    short8 qf = *(const short8*)qp;
    short8 kf = *(const short8*)kp;
    floatx16 C = {0.f, 0.f, 0.f, 0.f, 0.f, 0.f, 0.f, 0.f,
                  0.f, 0.f, 0.f, 0.f, 0.f, 0.f, 0.f, 0.f};
    C = __builtin_amdgcn_mfma_f32_32x32x16_bf16(kf, qf, C, 0, 0, 0);
    // C[r] = logits[f_r][g=lid], f_r = (r&3) + 8*(r>>2) + 4*half

    float m = -3.0e38f;
#pragma unroll
    for (int r = 0; r < 16; ++r) { logit_sum[r] += C[r]; m = fmaxf(m, C[r]); }
    m = fmaxf(m, __shfl_xor(m, 32));
    // overwrite C with exp(C - m): p[] folded into C to cut register pressure
    float l = 0.f;
#pragma unroll
    for (int r = 0; r < 16; ++r) { float e = __expf(C[r] - m); C[r] = e; l += e; }
    l += __shfl_xor(l, 32);
    const float inv = 1.0f / l;

    // ---- PV: x[g][d] += attn[f] * v[f][d], V broadcast from LDS ----
    float xacc[16];
#pragma unroll
    for (int d = 0; d < 16; ++d) xacc[d] = 0.f;
#pragma unroll
    for (int r = 0; r < 16; ++r) {
      float a = C[r] * inv;
      attn_sum[r] += a;
      int f = (r & 3) + ((r >> 2) << 3) + (half << 2);
      const unsigned short* vp = Vs + s_w * SLICE_U + f * 16;
      short8 vlo = *(const short8*)vp;
      short8 vhi = *(const short8*)(vp + 8);
#pragma unroll
      for (int j = 0; j < 8; ++j) {
        xacc[j]     = fmaf(a, bf2f(vlo[j]), xacc[j]);
        xacc[j + 8] = fmaf(a, bf2f(vhi[j]), xacc[j + 8]);
      }
    }
#pragma unroll
    for (int d = 0; d < 16; ++d) xacc[d] += __shfl_xor(xacc[d], 32);
    // store x into swizzled LDS stage; each half stores its 8 d's
#pragma unroll
    for (int j = 0; j < 8; ++j) {
      int d = (half << 3) + j;
      Xs[(lid * 16 + d) * 16 + sswz] = xacc[d];
    }
    __syncthreads();   // QKV free; Xs(h) ready

    if (h < 7) {       // stage next head (overlaps x writeout below)
      stage_tile(q, (unsigned*)Qs, b, h + 1, s0, tid, 0.25f);
      stage_tile(k, (unsigned*)Ks, b, h + 1, s0, tid, 1.0f);
      stage_tile(v, (unsigned*)Vs, b, h + 1, s0, tid, 1.0f);
    }
    // ---- coalesced x writeout for this h: 512 rows x 4 float4 ----
    {
      int it = tid;
#pragma unroll
      for (int c = 0; c < 2; ++c, it += 1024) {
        int row = it >> 2, sq = it & 3;
        int gg = row >> 4, dd = row & 15;
        float4 val = *(const float4*)&Xs[row * 16 + ((sq ^ (gg & 3)) << 2)];
        *(float4*)(xout + (((long)b * 32 + gg) * 128 + h * 16 + dd) * SQ_LEN +
                   s0 + (sq << 2)) = val;
      }
    }
    __syncthreads();   // Xs free for next h; staged QKV visible
  }

  // ---- head-mean writeout: stage sums in LDS (overlays QKV+Xs), float4 stores ----
  float* A = (float*)smem;        // attn_mean stage: 1024 rows x 16 s (64 KB)
  float* L = A + 16384;           // logits_mean stage (64 KB)
#pragma unroll
  for (int r = 0; r < 16; ++r) {
    int f = (r & 3) + ((r >> 2) << 3) + (half << 2);
    A[(lid * 32 + f) * 16 + sswz] = attn_sum[r] * 0.125f;
    L[(lid * 32 + f) * 16 + sswz] = logit_sum[r] * 0.125f;
  }
  __syncthreads();
  for (int it = tid; it < 8192; it += 1024) {
    int arr = it >> 12;
    int rem = it & 4095;
    int row = rem >> 2, sq = rem & 3;
    int gg = row >> 5, ff = row & 31;
    const float* SRC = arr ? L : A;
    float4 val = *(const float4*)&SRC[row * 16 + ((sq ^ (gg & 3)) << 2)];
    float* dst = (arr ? lout : aout) +
                 (((long)b * 32 + gg) * 32 + ff) * SQ_LEN + s0 + (sq << 2);
    *(float4*)dst = val;
  }
}

extern "C" void kernel_launch(void* const* d_in, const int* in_sizes, int n_in,
                              void* d_out, int out_size, void* d_ws, size_t ws_size,
                              hipStream_t stream) {
  const float* q = (const float*)d_in[0];
  const float* k = (const float*)d_in[1];
  const float* v = (const float*)d_in[2];
  float* xout = (float*)d_out;                   // (2,4096,4096)
  float* aout = xout + 33554432;                 // (2,32,32,4096)
  float* lout = xout + 41943040;                 // (2,32,32,4096)
  (void)hipFuncSetAttribute((const void*)attn_kernel,
                            hipFuncAttributeMaxDynamicSharedMemorySize, SMEM_BYTES);
  attn_kernel<<<dim3(SQ_LEN / TS, 2), 1024, SMEM_BYTES, stream>>>(q, k, v, xout, aout, lout);
}